// Round 4
// baseline (385.637 us; speedup 1.0000x reference)
//
#include <hip/hip_runtime.h>
#include <math.h>

// Problem constants: N=256, H*W=196, KB=512, CTRL=512, MEM=512, L=8, NMOD=9. f32.
constexpr int   NB   = 256;
constexpr int   HW   = 196;
constexpr int   KBC  = 512;
constexpr int   LSZ  = 8;
constexpr float EPSF = 1e-12f;

// ---------------- workspace layout (floats) ----------------
constexpr size_t S_ATT    = (size_t)NB * HW;                  // 50176
constexpr size_t OFF_ATT1 = 0;
constexpr size_t OFF_ATT2 = OFF_ATT1 + S_ATT;
constexpr size_t OFF_W1   = OFF_ATT2 + S_ATT;
constexpr size_t OFF_W2   = OFF_W1   + S_ATT;
constexpr size_t OFF_AF   = OFF_W2   + S_ATT;
constexpr size_t OFF_AT   = OFF_AF   + S_ATT;
constexpr size_t OFF_AS   = OFF_AT   + S_ATT;
constexpr size_t OFF_GP1  = OFF_AS   + S_ATT;                 // [4][256][2048] gemm1 partials
constexpr size_t OFF_KP   = OFF_GP1  + (size_t)4*NB*2048;     // [7][256][1024] katt partials
constexpr size_t OFF_A1   = OFF_KP   + (size_t)7*NB*1024;     // 256 x 1536
constexpr size_t OFF_A2   = OFF_A1   + (size_t)NB*1536;       // 256 x 1536
constexpr size_t OFF_G    = OFF_A2   + (size_t)NB*1536;       // 256 x 512
constexpr size_t OFF_P2   = OFF_G    + (size_t)NB*512;        // [16][256][512] gemm2 partials
constexpr size_t OFF_PF   = OFF_P2   + (size_t)16*NB*512;
constexpr size_t OFF_PB   = OFF_PF   + (size_t)NB*LSZ;
constexpr size_t OFF_PFB  = OFF_PB   + (size_t)NB*LSZ;
constexpr size_t OFF_SF2  = OFF_PFB  + (size_t)NB*LSZ;
constexpr size_t OFF_SFFB = OFF_SF2  + NB;
constexpr size_t OFF_CNT  = OFF_SFFB + NB;                    // 256 counters (int)
constexpr size_t WS_FLOATS= OFF_CNT  + NB;

static __device__ __forceinline__ float4 ld4(const float* p) {
    return *reinterpret_cast<const float4*>(p);
}

// ================================================================
// k_front (768 blocks, mod-3 striped):
//   r3==0 -> k_att for n=g3  (ptr variants, stack reads, softmax, cnt=0)
//   else  -> gemm1 split-K partials GP1[ks][256][2048]
// ================================================================
__global__ __launch_bounds__(256) void k_front(
    const float* __restrict__ stk, const float* __restrict__ ptrp,
    float* __restrict__ att1g, float* __restrict__ att2g,
    float* __restrict__ w1g, float* __restrict__ w2g,
    float* __restrict__ fws, float* __restrict__ bws, float* __restrict__ fbws,
    float* __restrict__ sf2ws, float* __restrict__ sffbws,
    int* __restrict__ cnt,
    const float* __restrict__ control,
    const float* __restrict__ B0, const float* __restrict__ B1,
    const float* __restrict__ B2, const float* __restrict__ B3,
    float* __restrict__ GP1)
{
    __shared__ float red[256];
    __shared__ float As[16][68];
    __shared__ float Bs[16][68];
    const int t = threadIdx.x;
    const int g3 = blockIdx.x / 3, r3 = blockIdx.x % 3;

    if (r3 == 0) {
        const int n = g3;
        if (t == 0) cnt[n] = 0;                       // reset last-block counter
        float pp[8], f[8], b[8], fb[8];
#pragma unroll
        for (int l = 0; l < 8; ++l) pp[l] = ptrp[n*8 + l];
        f[0] = 0.f;
#pragma unroll
        for (int l = 1; l < 8; ++l) f[l] = pp[l-1];
        f[7] += pp[7];
#pragma unroll
        for (int l = 0; l < 7; ++l) b[l] = pp[l+1];
        b[7] = 0.f;
        b[0] += pp[0];
#pragma unroll
        for (int l = 0; l < 7; ++l) fb[l] = f[l+1];
        fb[7] = 0.f;
        fb[0] += f[0];

        if (t == 0) {
            float sf2 = 0.f, sffb = 0.f;
#pragma unroll
            for (int l = 0; l < 8; ++l) {
                fws[n*8+l] = f[l]; bws[n*8+l] = b[l]; fbws[n*8+l] = fb[l];
                sf2  += f[l]*f[l];
                sffb += f[l]*fb[l];
            }
            sf2ws[n] = sf2; sffbws[n] = sffb;
        }

        float a1 = 0.f, a2 = 0.f;
        if (t < HW) {
            const float* sp = stk + ((size_t)n*HW + t) * 8;
            float4 v0 = ld4(sp), v1 = ld4(sp + 4);
            float s[8] = {v0.x, v0.y, v0.z, v0.w, v1.x, v1.y, v1.z, v1.w};
#pragma unroll
            for (int l = 0; l < 8; ++l) {
                a2 = fmaf(s[l], pp[l], a2);
                a1 = fmaf(s[l],  b[l], a1);
            }
            att1g[n*HW + t] = a1;
            att2g[n*HW + t] = a2;
        }

        red[t] = (t < HW) ? a1 : -3.0e38f;
        __syncthreads();
        for (int off = 128; off > 0; off >>= 1) { if (t < off) red[t] = fmaxf(red[t], red[t+off]); __syncthreads(); }
        const float m1 = red[0];
        __syncthreads();
        float e1 = (t < HW) ? __expf(a1 - m1) : 0.f;
        red[t] = e1;
        __syncthreads();
        for (int off = 128; off > 0; off >>= 1) { if (t < off) red[t] += red[t+off]; __syncthreads(); }
        const float s1 = red[0];
        __syncthreads();
        if (t < HW) w1g[n*HW + t] = e1 / s1;

        red[t] = (t < HW) ? a2 : -3.0e38f;
        __syncthreads();
        for (int off = 128; off > 0; off >>= 1) { if (t < off) red[t] = fmaxf(red[t], red[t+off]); __syncthreads(); }
        const float m2 = red[0];
        __syncthreads();
        float e2 = (t < HW) ? __expf(a2 - m2) : 0.f;
        red[t] = e2;
        __syncthreads();
        for (int off = 128; off > 0; off >>= 1) { if (t < off) red[t] += red[t+off]; __syncthreads(); }
        const float s2 = red[0];
        __syncthreads();
        if (t < HW) w2g[n*HW + t] = e2 / s2;
        return;
    }

    // ---- gemm1: BM=BN=64, BK=16, TM=TN=4, KCHUNK=128 ----
    const int idx = g3 * 2 + (r3 - 1);           // 0..511
    const int bn = (idx & 31) * 64;
    const int bm = ((idx >> 5) & 3) * 64;
    const int ks = idx >> 7;
    const int mat = bn >> 9;
    const float* B = (mat == 0) ? B0 : (mat == 1) ? B1 : (mat == 2) ? B2 : B3;
    const int kbase = ks * 128;
    const int bcol = bn & 511;

    const int tx = t & 15, ty = t >> 4;
    float acc[4][4] = {};
    const int ar = t >> 2, ac4 = (t & 3) * 4;
    const int br = t >> 4, bc4 = (t & 15) * 4;
    const float* Aptr = control + (size_t)(bm + ar) * 512 + kbase + ac4;
    const float* Bptr = B + (size_t)(kbase + br) * 512 + bcol + bc4;

    float4 aR = ld4(Aptr), bR = ld4(Bptr);
    for (int tile = 0; tile < 8; ++tile) {
        As[ac4+0][ar] = aR.x; As[ac4+1][ar] = aR.y; As[ac4+2][ar] = aR.z; As[ac4+3][ar] = aR.w;
        *reinterpret_cast<float4*>(&Bs[br][bc4]) = bR;
        __syncthreads();
        if (tile + 1 < 8) {
            aR = ld4(Aptr + (tile+1)*16);
            bR = ld4(Bptr + (size_t)(tile+1)*16*512);
        }
#pragma unroll
        for (int k = 0; k < 16; ++k) {
            float4 ra = *reinterpret_cast<const float4*>(&As[k][ty*4]);
            float4 rb = *reinterpret_cast<const float4*>(&Bs[k][tx*4]);
            const float av[4] = {ra.x, ra.y, ra.z, ra.w};
            const float bv[4] = {rb.x, rb.y, rb.z, rb.w};
#pragma unroll
            for (int i = 0; i < 4; ++i)
#pragma unroll
                for (int j = 0; j < 4; ++j)
                    acc[i][j] = fmaf(av[i], bv[j], acc[i][j]);
        }
        __syncthreads();
    }
#pragma unroll
    for (int i = 0; i < 4; ++i) {
        float4 v = make_float4(acc[i][0], acc[i][1], acc[i][2], acc[i][3]);
        *reinterpret_cast<float4*>(&GP1[((size_t)ks*NB + bm + ty*4 + i) * 2048 + bn + tx*4]) = v;
    }
}

// ================================================================
// k_kbA: first pass over kb (7 pixel-splits per n, 28 px/block, 7 px/wave).
// c_find reduced in-kernel from GP1 + bias. Last block per n (atomic) does
// the k_elt work: katt reduce, g, l2norm elts, prob-scaled A1'/A2'.
// ================================================================
__global__ __launch_bounds__(256) void k_kbA(
    const float* __restrict__ kb, const float* __restrict__ GP1,
    const float* __restrict__ find_ci_b,
    const float* __restrict__ w_find, const float* __restrict__ b_find,
    const float* __restrict__ w_scene, const float* __restrict__ b_scene,
    const float* __restrict__ w1g, const float* __restrict__ w2g,
    float* __restrict__ aF, float* __restrict__ aS, float* __restrict__ kpart,
    int* __restrict__ cnt,
    const float* __restrict__ tr_ci_b, const float* __restrict__ d1_ci_b,
    const float* __restrict__ d2_ci_b,
    const float* __restrict__ control, const float* __restrict__ prob,
    float* __restrict__ g, float* __restrict__ A1, float* __restrict__ A2)
{
    const int blk = blockIdx.x;
    const int n = blk / 7, sp = blk % 7;
    const int t = threadIdx.x, wv = t >> 6, lane = t & 63;
    const int k0 = lane * 8;
    const int p0 = sp * 28;

    __shared__ float w1s[28], w2s[28];
    __shared__ float kred[4][1024];
    __shared__ int amLast;
    if (t < 28) { w1s[t] = w1g[n*HW + p0 + t]; w2s[t] = w2g[n*HW + p0 + t]; }
    __syncthreads();

    float cf[8], wf[8], wsc[8];
    {
        const float* gp = GP1 + (size_t)n*2048 + k0;
        float4 a0 = ld4(gp),            a1 = ld4(gp + 4);
        float4 b0 = ld4(gp + 524288),   b1 = ld4(gp + 524288 + 4);
        float4 c0 = ld4(gp + 1048576),  c1 = ld4(gp + 1048576 + 4);
        float4 d0 = ld4(gp + 1572864),  d1 = ld4(gp + 1572864 + 4);
        float4 e0 = ld4(find_ci_b + k0), e1 = ld4(find_ci_b + k0 + 4);
        cf[0]=a0.x+b0.x+c0.x+d0.x+e0.x; cf[1]=a0.y+b0.y+c0.y+d0.y+e0.y;
        cf[2]=a0.z+b0.z+c0.z+d0.z+e0.z; cf[3]=a0.w+b0.w+c0.w+d0.w+e0.w;
        cf[4]=a1.x+b1.x+c1.x+d1.x+e1.x; cf[5]=a1.y+b1.y+c1.y+d1.y+e1.y;
        cf[6]=a1.z+b1.z+c1.z+d1.z+e1.z; cf[7]=a1.w+b1.w+c1.w+d1.w+e1.w;
        float4 f0 = ld4(w_find + k0), f1 = ld4(w_find + k0 + 4);
        wf[0]=f0.x; wf[1]=f0.y; wf[2]=f0.z; wf[3]=f0.w; wf[4]=f1.x; wf[5]=f1.y; wf[6]=f1.z; wf[7]=f1.w;
        float4 g0 = ld4(w_scene + k0), g1 = ld4(w_scene + k0 + 4);
        wsc[0]=g0.x; wsc[1]=g0.y; wsc[2]=g0.z; wsc[3]=g0.w; wsc[4]=g1.x; wsc[5]=g1.y; wsc[6]=g1.z; wsc[7]=g1.w;
    }
    const float bf = b_find[0], bs = b_scene[0];

    float k1a[8] = {0,0,0,0,0,0,0,0};
    float k2a[8] = {0,0,0,0,0,0,0,0};

    // 7 pixels per wave at stride 4 rows; 2-deep load pipeline.
    const float* base = kb + (((size_t)n*HW + p0 + wv) * KBC + k0);
    float4 c0 = ld4(base),            c1 = ld4(base + 4);
    float4 d0 = ld4(base + 4*KBC),    d1 = ld4(base + 4*KBC + 4);
#pragma unroll
    for (int i = 0; i < 7; ++i) {
        float4 e0 = {0,0,0,0}, e1 = {0,0,0,0};
        if (i + 2 < 7) {
            e0 = ld4(base + (size_t)(i+2)*4*KBC);
            e1 = ld4(base + (size_t)(i+2)*4*KBC + 4);
        }
        const int pl = p0 + wv + i*4;
        float kv[8] = {c0.x, c0.y, c0.z, c0.w, c1.x, c1.y, c1.z, c1.w};
        float sA = 0.f, sB = 0.f, sE = 0.f, sF = 0.f;
#pragma unroll
        for (int j = 0; j < 8; ++j) {
            const float t1 = kv[j] * cf[j];
            sA = fmaf(t1, t1, sA);
            sB = fmaf(t1, wf[j], sB);
            sE = fmaf(kv[j], kv[j], sE);
            sF = fmaf(kv[j], wsc[j], sF);
        }
        const float w1p = w1s[pl - p0], w2p = w2s[pl - p0];
#pragma unroll
        for (int j = 0; j < 8; ++j) {
            k1a[j] = fmaf(w1p, kv[j], k1a[j]);
            k2a[j] = fmaf(w2p, kv[j], k2a[j]);
        }
#pragma unroll
        for (int m = 1; m < 64; m <<= 1) {
            sA += __shfl_xor(sA, m);
            sB += __shfl_xor(sB, m);
            sE += __shfl_xor(sE, m);
            sF += __shfl_xor(sF, m);
        }
        if (lane == 0) {
            const size_t p = (size_t)n*HW + pl;
            aF[p] = sB / fmaxf(sqrtf(sA), EPSF) + bf;
            aS[p] = sF / fmaxf(sqrtf(sE), EPSF) + bs;
        }
        c0 = d0; c1 = d1; d0 = e0; d1 = e1;
    }
#pragma unroll
    for (int j = 0; j < 8; ++j) { kred[wv][k0 + j] = k1a[j]; kred[wv][512 + k0 + j] = k2a[j]; }
    __syncthreads();
    for (int idx = t; idx < 1024; idx += 256) {
        const float s = kred[0][idx] + kred[1][idx] + kred[2][idx] + kred[3][idx];
        kpart[((size_t)sp*NB + n) * 1024 + idx] = s;
    }

    // ---- last-block-per-n does the elt work ----
    __threadfence();
    if (t == 0) amLast = (atomicAdd(&cnt[n], 1) == 6);
    __syncthreads();
    if (!amLast) return;
    __threadfence();

    __shared__ float k1s[512], k2s[512];
    for (int idx = t; idx < 512; idx += 256) {
        float s1 = 0.f, s2 = 0.f;
#pragma unroll
        for (int spq = 0; spq < 7; ++spq) {
            const float* bp = kpart + ((size_t)spq*NB + n) * 1024;
            s1 += bp[idx];
            s2 += bp[512 + idx];
        }
        k1s[idx] = s1; k2s[idx] = s2;
    }
    __syncthreads();

    float v1[2], v2[2];
    float sum1 = 0.f, sum2 = 0.f;
#pragma unroll
    for (int i = 0; i < 2; ++i) {
        const int k = t + i*256;
        const float* gp = GP1 + (size_t)n*2048 + k;
        const float ct  = gp[512]  + gp[524288+512]  + gp[1048576+512]  + gp[1572864+512]  + tr_ci_b[k];
        const float cd1 = gp[1024] + gp[524288+1024] + gp[1048576+1024] + gp[1572864+1024] + d1_ci_b[k];
        const float cd2 = gp[1536] + gp[524288+1536] + gp[1048576+1536] + gp[1572864+1536] + d2_ci_b[k];
        g[(size_t)n*512 + k] = ct * k2s[k];
        v1[i] = cd1 * k2s[k];
        v2[i] = cd2 * k1s[k] * k2s[k];
        sum1 = fmaf(v1[i], v1[i], sum1);
        sum2 = fmaf(v2[i], v2[i], sum2);
    }
    __shared__ float r1[256], r2[256];
    r1[t] = sum1; r2[t] = sum2;
    __syncthreads();
    for (int off = 128; off > 0; off >>= 1) {
        if (t < off) { r1[t] += r1[t+off]; r2[t] += r2[t+off]; }
        __syncthreads();
    }
    const float n1 = fmaxf(sqrtf(r1[0]), EPSF);
    const float n2 = fmaxf(sqrtf(r2[0]), EPSF);
    const float p7 = prob[n*9 + 7], p8 = prob[n*9 + 8];
#pragma unroll
    for (int i = 0; i < 2; ++i) {
        const int k = t + i*256;
        const float c = control[(size_t)n*512 + k];
        A1[(size_t)n*1536 + k]        = p7 * c;
        A1[(size_t)n*1536 + 512 + k]  = p7 * v1[i] / n1;
        A1[(size_t)n*1536 + 1024 + k] = p7 * k2s[k];
        A2[(size_t)n*1536 + k]        = p8 * c;
        A2[(size_t)n*1536 + 512 + k]  = p8 * v2[i] / n2;
        A2[(size_t)n*1536 + 1024 + k] = p8 * k1s[k];
    }
}

// ================================================================
// k_mid (2304 blocks, mod-9 striped: 2 gemm + 7 kb per 9):
//   gemm role: fused mem GEMM [p7*A1 | p8*A2] @ vstack(W1,W2), split-K=16
//   kb role:   kb pass B (Transform attention), 7 splits per n
// ================================================================
__global__ __launch_bounds__(256) void k_mid(
    const float* __restrict__ kb, const float* __restrict__ g,
    const float* __restrict__ w_tr, const float* __restrict__ b_tr,
    float* __restrict__ aT,
    const float* __restrict__ A1, const float* __restrict__ A2,
    const float* __restrict__ W1, const float* __restrict__ W2,
    float* __restrict__ P2)
{
    __shared__ float As[16][68];
    __shared__ float Bs[16][68];
    const int t = threadIdx.x;
    const int g9 = blockIdx.x / 9, r9 = blockIdx.x % 9;

    if (r9 >= 2) {
        const int kidx = g9 * 7 + (r9 - 2);      // 0..1791
        const int n = kidx / 7, sp = kidx % 7;
        const int wv = t >> 6, lane = t & 63;
        const int k0 = lane * 8;
        const int p0 = sp * 28;
        float gv[8], wt[8];
        {
            float4 a0 = ld4(g + (size_t)n*512 + k0), a1 = ld4(g + (size_t)n*512 + k0 + 4);
            gv[0]=a0.x; gv[1]=a0.y; gv[2]=a0.z; gv[3]=a0.w; gv[4]=a1.x; gv[5]=a1.y; gv[6]=a1.z; gv[7]=a1.w;
            float4 b0 = ld4(w_tr + k0), b1 = ld4(w_tr + k0 + 4);
            wt[0]=b0.x; wt[1]=b0.y; wt[2]=b0.z; wt[3]=b0.w; wt[4]=b1.x; wt[5]=b1.y; wt[6]=b1.z; wt[7]=b1.w;
        }
        const float bt = b_tr[0];
        const float* base = kb + (((size_t)n*HW + p0 + wv) * KBC + k0);
        float4 c0 = ld4(base),            c1 = ld4(base + 4);
        float4 d0 = ld4(base + 4*KBC),    d1 = ld4(base + 4*KBC + 4);
#pragma unroll
        for (int i = 0; i < 7; ++i) {
            float4 e0 = {0,0,0,0}, e1 = {0,0,0,0};
            if (i + 2 < 7) {
                e0 = ld4(base + (size_t)(i+2)*4*KBC);
                e1 = ld4(base + (size_t)(i+2)*4*KBC + 4);
            }
            const int pl = p0 + wv + i*4;
            float kv[8] = {c0.x, c0.y, c0.z, c0.w, c1.x, c1.y, c1.z, c1.w};
            float sC = 0.f, sD = 0.f;
#pragma unroll
            for (int j = 0; j < 8; ++j) {
                const float u = kv[j] * gv[j];
                sC = fmaf(u, u, sC);
                sD = fmaf(u, wt[j], sD);
            }
#pragma unroll
            for (int m = 1; m < 64; m <<= 1) { sC += __shfl_xor(sC, m); sD += __shfl_xor(sD, m); }
            if (lane == 0) aT[(size_t)n*HW + pl] = sD / fmaxf(sqrtf(sC), EPSF) + bt;
            c0 = d0; c1 = d1; d0 = e0; d1 = e1;
        }
        return;
    }

    // ---- fused mem GEMM: KCHUNK=192, 16 splits ----
    const int idx = g9 * 2 + r9;                 // 0..511
    const int bn = (idx & 7) * 64;
    const int bm = ((idx >> 3) & 3) * 64;
    const int ks = idx >> 5;
    const int mat = ks >> 3;
    const float* A = mat ? A2 : A1;
    const float* B = mat ? W2 : W1;
    const int kbase = ks * 192 - mat * 1536;

    const int tx = t & 15, ty = t >> 4;
    float acc[4][4] = {};
    const int ar = t >> 2, ac4 = (t & 3) * 4;
    const int br = t >> 4, bc4 = (t & 15) * 4;
    const float* Aptr = A + (size_t)(bm + ar) * 1536 + kbase + ac4;
    const float* Bptr = B + (size_t)(kbase + br) * 512 + bn + bc4;

    float4 aR = ld4(Aptr), bR = ld4(Bptr);
    for (int tile = 0; tile < 12; ++tile) {
        As[ac4+0][ar] = aR.x; As[ac4+1][ar] = aR.y; As[ac4+2][ar] = aR.z; As[ac4+3][ar] = aR.w;
        *reinterpret_cast<float4*>(&Bs[br][bc4]) = bR;
        __syncthreads();
        if (tile + 1 < 12) {
            aR = ld4(Aptr + (tile+1)*16);
            bR = ld4(Bptr + (size_t)(tile+1)*16*512);
        }
#pragma unroll
        for (int k = 0; k < 16; ++k) {
            float4 ra = *reinterpret_cast<const float4*>(&As[k][ty*4]);
            float4 rb = *reinterpret_cast<const float4*>(&Bs[k][tx*4]);
            const float av[4] = {ra.x, ra.y, ra.z, ra.w};
            const float bv[4] = {rb.x, rb.y, rb.z, rb.w};
#pragma unroll
            for (int i = 0; i < 4; ++i)
#pragma unroll
                for (int j = 0; j < 4; ++j)
                    acc[i][j] = fmaf(av[i], bv[j], acc[i][j]);
        }
        __syncthreads();
    }
#pragma unroll
    for (int i = 0; i < 4; ++i) {
        float4 v = make_float4(acc[i][0], acc[i][1], acc[i][2], acc[i][3]);
        *reinterpret_cast<float4*>(&P2[((size_t)ks*NB + bm + ty*4 + i) * 512 + bn + tx*4]) = v;
    }
}

// ================================================================
// k_back: blocks 0..127 -> mem_avg; blocks 128..383 -> att/ptr assembly.
// ================================================================
__global__ __launch_bounds__(256) void k_back(
    const float* __restrict__ P2, const float* __restrict__ memprev,
    const float* __restrict__ prob,
    const float* __restrict__ mb1, const float* __restrict__ mb2,
    float* __restrict__ out_mem,
    const float* __restrict__ stk, const float* __restrict__ ptrp,
    const float* __restrict__ att1g, const float* __restrict__ att2g,
    const float* __restrict__ aFg, const float* __restrict__ aTg, const float* __restrict__ aSg,
    const float* __restrict__ fws, const float* __restrict__ bws, const float* __restrict__ fbws,
    const float* __restrict__ sf2ws, const float* __restrict__ sffbws,
    float* __restrict__ out_att, float* __restrict__ out_ptr)
{
    const int t = threadIdx.x;
    if (blockIdx.x < 128) {
        const size_t q = ((size_t)blockIdx.x * 256 + t) * 4;
        const int n = (int)(q >> 9), j = (int)(q & 511);
        const float p0 = prob[n*9 + 0], p7 = prob[n*9 + 7], p8 = prob[n*9 + 8];
        float4 s = ld4(P2 + q);
#pragma unroll
        for (int sp = 1; sp < 16; ++sp) {
            float4 v = ld4(P2 + (size_t)sp*131072 + q);
            s.x += v.x; s.y += v.y; s.z += v.z; s.w += v.w;
        }
        float4 mp = ld4(memprev + q);
        float4 w1 = ld4(mb1 + j), w2 = ld4(mb2 + j);
        float4 o;
        o.x = p0*mp.x + s.x + p7*w1.x + p8*w2.x;
        o.y = p0*mp.y + s.y + p7*w1.y + p8*w2.y;
        o.z = p0*mp.z + s.z + p7*w1.z + p8*w2.z;
        o.w = p0*mp.w + s.w + p7*w1.w + p8*w2.w;
        *reinterpret_cast<float4*>(&out_mem[q]) = o;
        return;
    }

    const int n = blockIdx.x - 128;
    __shared__ float pp[8], f[8], b[8], fb[8], pr[9], sc2[2];
    if (t < 8) { pp[t] = ptrp[n*8+t]; f[t] = fws[n*8+t]; b[t] = bws[n*8+t]; fb[t] = fbws[n*8+t]; }
    if (t < 9) pr[t] = prob[n*9+t];
    if (t == 0) { sc2[0] = sf2ws[n]; sc2[1] = sffbws[n]; }
    __syncthreads();

    if (t < HW) {
        const size_t p = (size_t)n*HW + t;
        const float* spt = stk + p*8;
        float4 v0 = ld4(spt), v1 = ld4(spt+4);
        float s[8] = {v0.x, v0.y, v0.z, v0.w, v1.x, v1.y, v1.z, v1.w};
        const float a1 = att1g[p], a2 = att2g[p];
        const float vaF = aFg[p], vaT = aTg[p], vaS = aSg[p];
        const float mn = fminf(a1, a2), mx = fmaxf(a1, a2);
        float rf = 0.f, rf2 = 0.f, rfb = 0.f, rffb = 0.f;
#pragma unroll
        for (int l = 0; l < 8; ++l) {
            rf   = fmaf(s[l], f[l],        rf);
            rf2  = fmaf(s[l], f[l]*f[l],   rf2);
            rfb  = fmaf(s[l], fb[l],       rfb);
            rffb = fmaf(s[l], f[l]*fb[l],  rffb);
        }
        const float att2p = vaF*sc2[0] + rf  - rf2;
        const float att1p = vaF*sc2[1] + rfb - rffb;
        const float mnF = fminf(att1p, att2p);
        const float c48 = pr[4] + pr[8];
        float o[8];
#pragma unroll
        for (int l = 0; l < 8; ++l) {
            const float sl = s[l];
            const float stkF = vaF*f[l] + sl*(1.f - f[l]);
            float r = (pr[0] + pr[7]) * sl;
            r = fmaf(pr[1], stkF, r);
            r = fmaf(pr[2], vaT*pp[l] + sl*(1.f - pp[l]), r);
            r = fmaf(pr[3], mnF*fb[l] + stkF*(1.f - fb[l]), r);
            r = fmaf(c48,   mn*b[l] + sl*(1.f - b[l]), r);
            r = fmaf(pr[5], mx*b[l] + sl*(1.f - b[l]), r);
            r = fmaf(pr[6], vaS*f[l] + sl*(1.f - f[l]), r);
            o[l] = r;
        }
        *reinterpret_cast<float4*>(out_att + p*8)     = make_float4(o[0], o[1], o[2], o[3]);
        *reinterpret_cast<float4*>(out_att + p*8 + 4) = make_float4(o[4], o[5], o[6], o[7]);
    }

    if (t == 0) {
        const float cpp = pr[0] + pr[2] + pr[7];
        const float cf  = pr[1] + pr[6];
        const float cb  = pr[4] + pr[5] + pr[8];
        float pa[8];
        float m = -3.0e38f;
#pragma unroll
        for (int l = 0; l < 8; ++l) {
            pa[l] = cpp*pp[l] + cf*f[l] + cb*b[l] + pr[3]*fb[l];
            m = fmaxf(m, pa[l]);
        }
        float ssum = 0.f;
#pragma unroll
        for (int l = 0; l < 8; ++l) { pa[l] = __expf(pa[l] - m); ssum += pa[l]; }
#pragma unroll
        for (int l = 0; l < 8; ++l) out_ptr[n*8 + l] = pa[l] / ssum;
    }
}

// ================================================================
extern "C" void kernel_launch(void* const* d_in, const int* in_sizes, int n_in,
                              void* d_out, int out_size, void* d_ws, size_t ws_size,
                              hipStream_t stream)
{
    (void)in_sizes; (void)n_in; (void)out_size;
    const float* control = (const float*)d_in[0];
    const float* kb      = (const float*)d_in[1];
    const float* prob    = (const float*)d_in[2];
    const float* memprev = (const float*)d_in[3];
    const float* stk     = (const float*)d_in[4];
    const float* ptrp    = (const float*)d_in[5];
    const float* find_w  = (const float*)d_in[6];
    const float* find_b  = (const float*)d_in[7];
    const float* findc_w = (const float*)d_in[8];
    const float* findc_b = (const float*)d_in[9];
    const float* tr_w    = (const float*)d_in[10];
    const float* tr_b    = (const float*)d_in[11];
    const float* trc_w   = (const float*)d_in[12];
    const float* trc_b   = (const float*)d_in[13];
    const float* sc_w    = (const float*)d_in[14];
    const float* sc_b    = (const float*)d_in[15];
    const float* d1_w    = (const float*)d_in[16];
    const float* d1_b    = (const float*)d_in[17];
    const float* d1m_w   = (const float*)d_in[18];
    const float* d1m_b   = (const float*)d_in[19];
    const float* d2_w    = (const float*)d_in[20];
    const float* d2_b    = (const float*)d_in[21];
    const float* d2m_w   = (const float*)d_in[22];
    const float* d2m_b   = (const float*)d_in[23];

    if (ws_size < WS_FLOATS * sizeof(float)) return;

    float* ws    = (float*)d_ws;
    float* att1g = ws + OFF_ATT1;
    float* att2g = ws + OFF_ATT2;
    float* w1g   = ws + OFF_W1;
    float* w2g   = ws + OFF_W2;
    float* aF    = ws + OFF_AF;
    float* aT    = ws + OFF_AT;
    float* aS    = ws + OFF_AS;
    float* GP1   = ws + OFF_GP1;
    float* kpart = ws + OFF_KP;
    float* A1    = ws + OFF_A1;
    float* A2    = ws + OFF_A2;
    float* g     = ws + OFF_G;
    float* P2    = ws + OFF_P2;
    float* fws   = ws + OFF_PF;
    float* bws   = ws + OFF_PB;
    float* fbws  = ws + OFF_PFB;
    float* sf2   = ws + OFF_SF2;
    float* sffb  = ws + OFF_SFFB;
    int*   cnt   = (int*)(ws + OFF_CNT);

    float* out_att = (float*)d_out;
    float* out_ptr = out_att + (size_t)NB*HW*LSZ;
    float* out_mem = out_ptr + (size_t)NB*LSZ;

    // 1. k_att ∪ gemm1-partials (mod-3 striped; also zeroes cnt)
    k_front<<<768, 256, 0, stream>>>(
        stk, ptrp, att1g, att2g, w1g, w2g, fws, bws, fbws, sf2, sffb, cnt,
        control, find_w, tr_w, d1_w, d2_w, GP1);
    // 2. kb pass A + fused last-block elt
    k_kbA<<<NB*7, 256, 0, stream>>>(kb, GP1, find_b, findc_w, findc_b, sc_w, sc_b,
                                    w1g, w2g, aF, aS, kpart, cnt,
                                    tr_b, d1_b, d2_b, control, prob, g, A1, A2);
    // 3. kb pass B ∪ fused mem-GEMM partials (mod-9 striped)
    k_mid<<<2304, 256, 0, stream>>>(kb, g, trc_w, trc_b, aT,
                                    A1, A2, d1m_w, d2m_w, P2);
    // 4. mem_avg ∪ att_stack_avg/stack_ptr_avg
    k_back<<<128 + 256, 256, 0, stream>>>(P2, memprev, prob, d1m_b, d2m_b, out_mem,
                                          stk, ptrp, att1g, att2g, aF, aT, aS,
                                          fws, bws, fbws, sf2, sffb, out_att, out_ptr);
}

// Round 5
// 78.492 us; speedup vs baseline: 4.9131x; 4.9131x over previous
//
#include <hip/hip_runtime.h>
#include <math.h>

// Problem constants: N=256, H*W=196, KB=512, CTRL=512, MEM=512, L=8, NMOD=9. f32.
constexpr int   NB   = 256;
constexpr int   HW   = 196;
constexpr int   KBC  = 512;
constexpr int   LSZ  = 8;
constexpr float EPSF = 1e-12f;

// ---------------- workspace layout (floats) ----------------
constexpr size_t S_ATT    = (size_t)NB * HW;                  // 50176
constexpr size_t OFF_ATT1 = 0;
constexpr size_t OFF_ATT2 = OFF_ATT1 + S_ATT;
constexpr size_t OFF_W1   = OFF_ATT2 + S_ATT;
constexpr size_t OFF_W2   = OFF_W1   + S_ATT;
constexpr size_t OFF_AF   = OFF_W2   + S_ATT;
constexpr size_t OFF_AT   = OFF_AF   + S_ATT;
constexpr size_t OFF_AS   = OFF_AT   + S_ATT;
constexpr size_t OFF_GP1  = OFF_AS   + S_ATT;                 // [4][256][2048] gemm1 partials
constexpr size_t OFF_KP   = OFF_GP1  + (size_t)4*NB*2048;     // [4][256][1024] katt partials
constexpr size_t OFF_A1   = OFF_KP   + (size_t)4*NB*1024;     // 256 x 1536
constexpr size_t OFF_A2   = OFF_A1   + (size_t)NB*1536;       // 256 x 1536
constexpr size_t OFF_G    = OFF_A2   + (size_t)NB*1536;       // 256 x 512
constexpr size_t OFF_P2   = OFF_G    + (size_t)NB*512;        // [16][256][512] gemm2 partials
constexpr size_t OFF_PF   = OFF_P2   + (size_t)16*NB*512;
constexpr size_t OFF_PB   = OFF_PF   + (size_t)NB*LSZ;
constexpr size_t OFF_PFB  = OFF_PB   + (size_t)NB*LSZ;
constexpr size_t OFF_SF2  = OFF_PFB  + (size_t)NB*LSZ;
constexpr size_t OFF_SFFB = OFF_SF2  + NB;
constexpr size_t WS_FLOATS= OFF_SFFB + NB;

static __device__ __forceinline__ float4 ld4(const float* p) {
    return *reinterpret_cast<const float4*>(p);
}

// ================================================================
// k_front: blocks 0..255 -> k_att (per-n ptr variants, stack reads, softmax)
//          blocks 256..767 -> gemm1 split-K partials
//             GP1[ks][256][2048] = control @ [find|tr|d1|d2]_ci (no bias)
// ================================================================
__global__ __launch_bounds__(256) void k_front(
    const float* __restrict__ stk, const float* __restrict__ ptrp,
    float* __restrict__ att1g, float* __restrict__ att2g,
    float* __restrict__ w1g, float* __restrict__ w2g,
    float* __restrict__ fws, float* __restrict__ bws, float* __restrict__ fbws,
    float* __restrict__ sf2ws, float* __restrict__ sffbws,
    const float* __restrict__ control,
    const float* __restrict__ B0, const float* __restrict__ B1,
    const float* __restrict__ B2, const float* __restrict__ B3,
    float* __restrict__ GP1)
{
    __shared__ float red[256];
    __shared__ float As[16][68];
    __shared__ float Bs[16][68];
    const int t = threadIdx.x;

    if (blockIdx.x < 256) {
        const int n = blockIdx.x;
        float pp[8], f[8], b[8], fb[8];
#pragma unroll
        for (int l = 0; l < 8; ++l) pp[l] = ptrp[n*8 + l];
        f[0] = 0.f;
#pragma unroll
        for (int l = 1; l < 8; ++l) f[l] = pp[l-1];
        f[7] += pp[7];
#pragma unroll
        for (int l = 0; l < 7; ++l) b[l] = pp[l+1];
        b[7] = 0.f;
        b[0] += pp[0];
#pragma unroll
        for (int l = 0; l < 7; ++l) fb[l] = f[l+1];
        fb[7] = 0.f;
        fb[0] += f[0];

        if (t == 0) {
            float sf2 = 0.f, sffb = 0.f;
#pragma unroll
            for (int l = 0; l < 8; ++l) {
                fws[n*8+l] = f[l]; bws[n*8+l] = b[l]; fbws[n*8+l] = fb[l];
                sf2  += f[l]*f[l];
                sffb += f[l]*fb[l];
            }
            sf2ws[n] = sf2; sffbws[n] = sffb;
        }

        float a1 = 0.f, a2 = 0.f;
        if (t < HW) {
            const float* sp = stk + ((size_t)n*HW + t) * 8;
            float4 v0 = ld4(sp), v1 = ld4(sp + 4);
            float s[8] = {v0.x, v0.y, v0.z, v0.w, v1.x, v1.y, v1.z, v1.w};
#pragma unroll
            for (int l = 0; l < 8; ++l) {
                a2 = fmaf(s[l], pp[l], a2);
                a1 = fmaf(s[l],  b[l], a1);
            }
            att1g[n*HW + t] = a1;
            att2g[n*HW + t] = a2;
        }

        red[t] = (t < HW) ? a1 : -3.0e38f;
        __syncthreads();
        for (int off = 128; off > 0; off >>= 1) { if (t < off) red[t] = fmaxf(red[t], red[t+off]); __syncthreads(); }
        const float m1 = red[0];
        __syncthreads();
        float e1 = (t < HW) ? __expf(a1 - m1) : 0.f;
        red[t] = e1;
        __syncthreads();
        for (int off = 128; off > 0; off >>= 1) { if (t < off) red[t] += red[t+off]; __syncthreads(); }
        const float s1 = red[0];
        __syncthreads();
        if (t < HW) w1g[n*HW + t] = e1 / s1;

        red[t] = (t < HW) ? a2 : -3.0e38f;
        __syncthreads();
        for (int off = 128; off > 0; off >>= 1) { if (t < off) red[t] = fmaxf(red[t], red[t+off]); __syncthreads(); }
        const float m2 = red[0];
        __syncthreads();
        float e2 = (t < HW) ? __expf(a2 - m2) : 0.f;
        red[t] = e2;
        __syncthreads();
        for (int off = 128; off > 0; off >>= 1) { if (t < off) red[t] += red[t+off]; __syncthreads(); }
        const float s2 = red[0];
        __syncthreads();
        if (t < HW) w2g[n*HW + t] = e2 / s2;
        return;
    }

    // ---- gemm1: BM=BN=64, BK=16, TM=TN=4, KCHUNK=128 ----
    const int idx = blockIdx.x - 256;            // 0..511
    const int bn = (idx & 31) * 64;
    const int bm = ((idx >> 5) & 3) * 64;
    const int ks = idx >> 7;
    const int mat = bn >> 9;
    const float* B = (mat == 0) ? B0 : (mat == 1) ? B1 : (mat == 2) ? B2 : B3;
    const int kbase = ks * 128;
    const int bcol = bn & 511;

    const int tx = t & 15, ty = t >> 4;
    float acc[4][4] = {};
    const int ar = t >> 2, ac4 = (t & 3) * 4;
    const int br = t >> 4, bc4 = (t & 15) * 4;
    const float* Aptr = control + (size_t)(bm + ar) * 512 + kbase + ac4;
    const float* Bptr = B + (size_t)(kbase + br) * 512 + bcol + bc4;

    float4 aR = ld4(Aptr), bR = ld4(Bptr);
    for (int tile = 0; tile < 8; ++tile) {
        As[ac4+0][ar] = aR.x; As[ac4+1][ar] = aR.y; As[ac4+2][ar] = aR.z; As[ac4+3][ar] = aR.w;
        *reinterpret_cast<float4*>(&Bs[br][bc4]) = bR;
        __syncthreads();
        if (tile + 1 < 8) {
            aR = ld4(Aptr + (tile+1)*16);
            bR = ld4(Bptr + (size_t)(tile+1)*16*512);
        }
#pragma unroll
        for (int k = 0; k < 16; ++k) {
            float4 ra = *reinterpret_cast<const float4*>(&As[k][ty*4]);
            float4 rb = *reinterpret_cast<const float4*>(&Bs[k][tx*4]);
            const float av[4] = {ra.x, ra.y, ra.z, ra.w};
            const float bv[4] = {rb.x, rb.y, rb.z, rb.w};
#pragma unroll
            for (int i = 0; i < 4; ++i)
#pragma unroll
                for (int j = 0; j < 4; ++j)
                    acc[i][j] = fmaf(av[i], bv[j], acc[i][j]);
        }
        __syncthreads();
    }
#pragma unroll
    for (int i = 0; i < 4; ++i) {
        float4 v = make_float4(acc[i][0], acc[i][1], acc[i][2], acc[i][3]);
        *reinterpret_cast<float4*>(&GP1[((size_t)ks*NB + bm + ty*4 + i) * 2048 + bn + tx*4]) = v;
    }
}

// ================================================================
// k_kbA: first pass over kb. c_find reduced in-kernel from GP1 + bias.
// grid = 1024 (4 pixel-splits per n), 256 threads.
// ================================================================
__global__ __launch_bounds__(256) void k_kbA(
    const float* __restrict__ kb, const float* __restrict__ GP1,
    const float* __restrict__ find_ci_b,
    const float* __restrict__ w_find, const float* __restrict__ b_find,
    const float* __restrict__ w_scene, const float* __restrict__ b_scene,
    const float* __restrict__ w1g, const float* __restrict__ w2g,
    float* __restrict__ aF, float* __restrict__ aS, float* __restrict__ kpart)
{
    const int blk = blockIdx.x;
    const int n = blk >> 2, sp = blk & 3;
    const int t = threadIdx.x, wv = t >> 6, lane = t & 63;
    const int k0 = lane * 8;
    const int p0 = sp * 49;

    __shared__ float w1s[49], w2s[49];
    __shared__ float kred[4][1024];
    if (t < 49) { w1s[t] = w1g[n*HW + p0 + t]; w2s[t] = w2g[n*HW + p0 + t]; }
    __syncthreads();

    float cf[8], wf[8], wsc[8];
    {
        const float* gp = GP1 + (size_t)n*2048 + k0;
        float4 a0 = ld4(gp),            a1 = ld4(gp + 4);
        float4 b0 = ld4(gp + 524288),   b1 = ld4(gp + 524288 + 4);
        float4 c0 = ld4(gp + 1048576),  c1 = ld4(gp + 1048576 + 4);
        float4 d0 = ld4(gp + 1572864),  d1 = ld4(gp + 1572864 + 4);
        float4 e0 = ld4(find_ci_b + k0), e1 = ld4(find_ci_b + k0 + 4);
        cf[0]=a0.x+b0.x+c0.x+d0.x+e0.x; cf[1]=a0.y+b0.y+c0.y+d0.y+e0.y;
        cf[2]=a0.z+b0.z+c0.z+d0.z+e0.z; cf[3]=a0.w+b0.w+c0.w+d0.w+e0.w;
        cf[4]=a1.x+b1.x+c1.x+d1.x+e1.x; cf[5]=a1.y+b1.y+c1.y+d1.y+e1.y;
        cf[6]=a1.z+b1.z+c1.z+d1.z+e1.z; cf[7]=a1.w+b1.w+c1.w+d1.w+e1.w;
        float4 f0 = ld4(w_find + k0), f1 = ld4(w_find + k0 + 4);
        wf[0]=f0.x; wf[1]=f0.y; wf[2]=f0.z; wf[3]=f0.w; wf[4]=f1.x; wf[5]=f1.y; wf[6]=f1.z; wf[7]=f1.w;
        float4 g0 = ld4(w_scene + k0), g1 = ld4(w_scene + k0 + 4);
        wsc[0]=g0.x; wsc[1]=g0.y; wsc[2]=g0.z; wsc[3]=g0.w; wsc[4]=g1.x; wsc[5]=g1.y; wsc[6]=g1.z; wsc[7]=g1.w;
    }
    const float bf = b_find[0], bs = b_scene[0];

    float k1a[8] = {0,0,0,0,0,0,0,0};
    float k2a[8] = {0,0,0,0,0,0,0,0};

    const float* src0 = kb + (((size_t)n*HW + p0 + wv) * KBC + k0);
    float4 v0 = ld4(src0), v1 = ld4(src0 + 4);
    for (int pl = wv; pl < 49; pl += 4) {
        float4 n0, n1;
        if (pl + 4 < 49) {
            const float* ns = kb + (((size_t)n*HW + p0 + pl + 4) * KBC + k0);
            n0 = ld4(ns); n1 = ld4(ns + 4);
        }
        float kv[8] = {v0.x, v0.y, v0.z, v0.w, v1.x, v1.y, v1.z, v1.w};
        float sA = 0.f, sB = 0.f, sE = 0.f, sF = 0.f;
#pragma unroll
        for (int j = 0; j < 8; ++j) {
            const float t1 = kv[j] * cf[j];
            sA = fmaf(t1, t1, sA);
            sB = fmaf(t1, wf[j], sB);
            sE = fmaf(kv[j], kv[j], sE);
            sF = fmaf(kv[j], wsc[j], sF);
        }
        const float w1p = w1s[pl], w2p = w2s[pl];
#pragma unroll
        for (int j = 0; j < 8; ++j) {
            k1a[j] = fmaf(w1p, kv[j], k1a[j]);
            k2a[j] = fmaf(w2p, kv[j], k2a[j]);
        }
#pragma unroll
        for (int m = 1; m < 64; m <<= 1) {
            sA += __shfl_xor(sA, m);
            sB += __shfl_xor(sB, m);
            sE += __shfl_xor(sE, m);
            sF += __shfl_xor(sF, m);
        }
        if (lane == 0) {
            const size_t p = (size_t)n*HW + p0 + pl;
            aF[p] = sB / fmaxf(sqrtf(sA), EPSF) + bf;
            aS[p] = sF / fmaxf(sqrtf(sE), EPSF) + bs;
        }
        v0 = n0; v1 = n1;
    }
#pragma unroll
    for (int j = 0; j < 8; ++j) { kred[wv][k0 + j] = k1a[j]; kred[wv][512 + k0 + j] = k2a[j]; }
    __syncthreads();
    for (int idx = t; idx < 1024; idx += 256) {
        const float s = kred[0][idx] + kred[1][idx] + kred[2][idx] + kred[3][idx];
        kpart[((size_t)sp*NB + n) * 1024 + idx] = s;
    }
}

// ================================================================
// k_elt: reduce katt partials; reduce GP1 for c_tr/c_d1/c_d2 (+biases);
// g = c_tr*katt2; l2norm elts; A1' = p7*[ctrl|elt1|katt2], A2' = p8*[...].
// ================================================================
__global__ __launch_bounds__(256) void k_elt(
    const float* __restrict__ kpart, const float* __restrict__ GP1,
    const float* __restrict__ tr_ci_b, const float* __restrict__ d1_ci_b,
    const float* __restrict__ d2_ci_b,
    const float* __restrict__ control, const float* __restrict__ prob,
    float* __restrict__ g, float* __restrict__ A1, float* __restrict__ A2)
{
    const int n = blockIdx.x;
    const int t = threadIdx.x;
    __shared__ float k1s[512], k2s[512];
    for (int idx = t; idx < 512; idx += 256) {
        float s1 = 0.f, s2 = 0.f;
#pragma unroll
        for (int sp = 0; sp < 4; ++sp) {
            const float* base = kpart + ((size_t)sp*NB + n) * 1024;
            s1 += base[idx];
            s2 += base[512 + idx];
        }
        k1s[idx] = s1; k2s[idx] = s2;
    }
    __syncthreads();

    float v1[2], v2[2];
    float sum1 = 0.f, sum2 = 0.f;
#pragma unroll
    for (int i = 0; i < 2; ++i) {
        const int k = t + i*256;
        const float* gp = GP1 + (size_t)n*2048 + k;
        const float ct  = gp[512]  + gp[524288+512]  + gp[1048576+512]  + gp[1572864+512]  + tr_ci_b[k];
        const float cd1 = gp[1024] + gp[524288+1024] + gp[1048576+1024] + gp[1572864+1024] + d1_ci_b[k];
        const float cd2 = gp[1536] + gp[524288+1536] + gp[1048576+1536] + gp[1572864+1536] + d2_ci_b[k];
        g[(size_t)n*512 + k] = ct * k2s[k];
        v1[i] = cd1 * k2s[k];
        v2[i] = cd2 * k1s[k] * k2s[k];
        sum1 = fmaf(v1[i], v1[i], sum1);
        sum2 = fmaf(v2[i], v2[i], sum2);
    }
    __shared__ float r1[256], r2[256];
    r1[t] = sum1; r2[t] = sum2;
    __syncthreads();
    for (int off = 128; off > 0; off >>= 1) {
        if (t < off) { r1[t] += r1[t+off]; r2[t] += r2[t+off]; }
        __syncthreads();
    }
    const float n1 = fmaxf(sqrtf(r1[0]), EPSF);
    const float n2 = fmaxf(sqrtf(r2[0]), EPSF);
    const float p7 = prob[n*9 + 7], p8 = prob[n*9 + 8];
#pragma unroll
    for (int i = 0; i < 2; ++i) {
        const int k = t + i*256;
        const float c = control[(size_t)n*512 + k];
        A1[(size_t)n*1536 + k]        = p7 * c;
        A1[(size_t)n*1536 + 512 + k]  = p7 * v1[i] / n1;
        A1[(size_t)n*1536 + 1024 + k] = p7 * k2s[k];
        A2[(size_t)n*1536 + k]        = p8 * c;
        A2[(size_t)n*1536 + 512 + k]  = p8 * v2[i] / n2;
        A2[(size_t)n*1536 + 1024 + k] = p8 * k1s[k];
    }
}

// ================================================================
// k_mid (1536 blocks, mod-3 striped: 1 gemm + 2 kb per 3):
//   r3==0 -> fused mem GEMM [p7*A1 | p8*A2] @ vstack(W1,W2), split-K=16
//   else  -> kb pass B (Transform attention), 4 splits per n
// Striping interleaves compute-bound gemm with memory-bound kb on every
// CU from t=0 (m114 MFMA/VALU-style co-schedule, here VALU/VMEM).
// ================================================================
__global__ __launch_bounds__(256) void k_mid(
    const float* __restrict__ kb, const float* __restrict__ g,
    const float* __restrict__ w_tr, const float* __restrict__ b_tr,
    float* __restrict__ aT,
    const float* __restrict__ A1, const float* __restrict__ A2,
    const float* __restrict__ W1, const float* __restrict__ W2,
    float* __restrict__ P2)
{
    __shared__ float As[16][68];
    __shared__ float Bs[16][68];
    const int t = threadIdx.x;
    const int g3 = blockIdx.x / 3, r3 = blockIdx.x % 3;

    if (r3 != 0) {
        const int kidx = g3 * 2 + (r3 - 1);      // 0..1023
        const int n = kidx >> 2, sp = kidx & 3;
        const int wv = t >> 6, lane = t & 63;
        const int k0 = lane * 8;
        const int p0 = sp * 49;
        float gv[8], wt[8];
        {
            float4 a0 = ld4(g + (size_t)n*512 + k0), a1 = ld4(g + (size_t)n*512 + k0 + 4);
            gv[0]=a0.x; gv[1]=a0.y; gv[2]=a0.z; gv[3]=a0.w; gv[4]=a1.x; gv[5]=a1.y; gv[6]=a1.z; gv[7]=a1.w;
            float4 b0 = ld4(w_tr + k0), b1 = ld4(w_tr + k0 + 4);
            wt[0]=b0.x; wt[1]=b0.y; wt[2]=b0.z; wt[3]=b0.w; wt[4]=b1.x; wt[5]=b1.y; wt[6]=b1.z; wt[7]=b1.w;
        }
        const float bt = b_tr[0];
        const float* src0 = kb + (((size_t)n*HW + p0 + wv) * KBC + k0);
        float4 v0 = ld4(src0), v1 = ld4(src0 + 4);
        for (int pl = wv; pl < 49; pl += 4) {
            float4 n0, n1;
            if (pl + 4 < 49) {
                const float* ns = kb + (((size_t)n*HW + p0 + pl + 4) * KBC + k0);
                n0 = ld4(ns); n1 = ld4(ns + 4);
            }
            float kv[8] = {v0.x, v0.y, v0.z, v0.w, v1.x, v1.y, v1.z, v1.w};
            float sC = 0.f, sD = 0.f;
#pragma unroll
            for (int j = 0; j < 8; ++j) {
                const float u = kv[j] * gv[j];
                sC = fmaf(u, u, sC);
                sD = fmaf(u, wt[j], sD);
            }
#pragma unroll
            for (int m = 1; m < 64; m <<= 1) { sC += __shfl_xor(sC, m); sD += __shfl_xor(sD, m); }
            if (lane == 0) aT[(size_t)n*HW + p0 + pl] = sD / fmaxf(sqrtf(sC), EPSF) + bt;
            v0 = n0; v1 = n1;
        }
        return;
    }

    // ---- fused mem GEMM: KCHUNK=192, 16 splits ----
    const int idx = g3;                          // 0..511
    const int bn = (idx & 7) * 64;
    const int bm = ((idx >> 3) & 3) * 64;
    const int ks = idx >> 5;
    const int mat = ks >> 3;
    const float* A = mat ? A2 : A1;
    const float* B = mat ? W2 : W1;
    const int kbase = ks * 192 - mat * 1536;

    const int tx = t & 15, ty = t >> 4;
    float acc[4][4] = {};
    const int ar = t >> 2, ac4 = (t & 3) * 4;
    const int br = t >> 4, bc4 = (t & 15) * 4;
    const float* Aptr = A + (size_t)(bm + ar) * 1536 + kbase + ac4;
    const float* Bptr = B + (size_t)(kbase + br) * 512 + bn + bc4;

    float4 aR = ld4(Aptr), bR = ld4(Bptr);
    for (int tile = 0; tile < 12; ++tile) {
        As[ac4+0][ar] = aR.x; As[ac4+1][ar] = aR.y; As[ac4+2][ar] = aR.z; As[ac4+3][ar] = aR.w;
        *reinterpret_cast<float4*>(&Bs[br][bc4]) = bR;
        __syncthreads();
        if (tile + 1 < 12) {
            aR = ld4(Aptr + (tile+1)*16);
            bR = ld4(Bptr + (size_t)(tile+1)*16*512);
        }
#pragma unroll
        for (int k = 0; k < 16; ++k) {
            float4 ra = *reinterpret_cast<const float4*>(&As[k][ty*4]);
            float4 rb = *reinterpret_cast<const float4*>(&Bs[k][tx*4]);
            const float av[4] = {ra.x, ra.y, ra.z, ra.w};
            const float bv[4] = {rb.x, rb.y, rb.z, rb.w};
#pragma unroll
            for (int i = 0; i < 4; ++i)
#pragma unroll
                for (int j = 0; j < 4; ++j)
                    acc[i][j] = fmaf(av[i], bv[j], acc[i][j]);
        }
        __syncthreads();
    }
#pragma unroll
    for (int i = 0; i < 4; ++i) {
        float4 v = make_float4(acc[i][0], acc[i][1], acc[i][2], acc[i][3]);
        *reinterpret_cast<float4*>(&P2[((size_t)ks*NB + bm + ty*4 + i) * 512 + bn + tx*4]) = v;
    }
}

// ================================================================
// k_back: blocks 0..127 -> mem_avg; blocks 128..383 -> att/ptr assembly.
// ================================================================
__global__ __launch_bounds__(256) void k_back(
    const float* __restrict__ P2, const float* __restrict__ memprev,
    const float* __restrict__ prob,
    const float* __restrict__ mb1, const float* __restrict__ mb2,
    float* __restrict__ out_mem,
    const float* __restrict__ stk, const float* __restrict__ ptrp,
    const float* __restrict__ att1g, const float* __restrict__ att2g,
    const float* __restrict__ aFg, const float* __restrict__ aTg, const float* __restrict__ aSg,
    const float* __restrict__ fws, const float* __restrict__ bws, const float* __restrict__ fbws,
    const float* __restrict__ sf2ws, const float* __restrict__ sffbws,
    float* __restrict__ out_att, float* __restrict__ out_ptr)
{
    const int t = threadIdx.x;
    if (blockIdx.x < 128) {
        const size_t q = ((size_t)blockIdx.x * 256 + t) * 4;
        const int n = (int)(q >> 9), j = (int)(q & 511);
        const float p0 = prob[n*9 + 0], p7 = prob[n*9 + 7], p8 = prob[n*9 + 8];
        float4 s = ld4(P2 + q);
#pragma unroll
        for (int sp = 1; sp < 16; ++sp) {
            float4 v = ld4(P2 + (size_t)sp*131072 + q);
            s.x += v.x; s.y += v.y; s.z += v.z; s.w += v.w;
        }
        float4 mp = ld4(memprev + q);
        float4 w1 = ld4(mb1 + j), w2 = ld4(mb2 + j);
        float4 o;
        o.x = p0*mp.x + s.x + p7*w1.x + p8*w2.x;
        o.y = p0*mp.y + s.y + p7*w1.y + p8*w2.y;
        o.z = p0*mp.z + s.z + p7*w1.z + p8*w2.z;
        o.w = p0*mp.w + s.w + p7*w1.w + p8*w2.w;
        *reinterpret_cast<float4*>(&out_mem[q]) = o;
        return;
    }

    const int n = blockIdx.x - 128;
    __shared__ float pp[8], f[8], b[8], fb[8], pr[9], sc2[2];
    if (t < 8) { pp[t] = ptrp[n*8+t]; f[t] = fws[n*8+t]; b[t] = bws[n*8+t]; fb[t] = fbws[n*8+t]; }
    if (t < 9) pr[t] = prob[n*9+t];
    if (t == 0) { sc2[0] = sf2ws[n]; sc2[1] = sffbws[n]; }
    __syncthreads();

    if (t < HW) {
        const size_t p = (size_t)n*HW + t;
        const float* spt = stk + p*8;
        float4 v0 = ld4(spt), v1 = ld4(spt+4);
        float s[8] = {v0.x, v0.y, v0.z, v0.w, v1.x, v1.y, v1.z, v1.w};
        const float a1 = att1g[p], a2 = att2g[p];
        const float vaF = aFg[p], vaT = aTg[p], vaS = aSg[p];
        const float mn = fminf(a1, a2), mx = fmaxf(a1, a2);
        float rf = 0.f, rf2 = 0.f, rfb = 0.f, rffb = 0.f;
#pragma unroll
        for (int l = 0; l < 8; ++l) {
            rf   = fmaf(s[l], f[l],        rf);
            rf2  = fmaf(s[l], f[l]*f[l],   rf2);
            rfb  = fmaf(s[l], fb[l],       rfb);
            rffb = fmaf(s[l], f[l]*fb[l],  rffb);
        }
        const float att2p = vaF*sc2[0] + rf  - rf2;
        const float att1p = vaF*sc2[1] + rfb - rffb;
        const float mnF = fminf(att1p, att2p);
        const float c48 = pr[4] + pr[8];
        float o[8];
#pragma unroll
        for (int l = 0; l < 8; ++l) {
            const float sl = s[l];
            const float stkF = vaF*f[l] + sl*(1.f - f[l]);
            float r = (pr[0] + pr[7]) * sl;
            r = fmaf(pr[1], stkF, r);
            r = fmaf(pr[2], vaT*pp[l] + sl*(1.f - pp[l]), r);
            r = fmaf(pr[3], mnF*fb[l] + stkF*(1.f - fb[l]), r);
            r = fmaf(c48,   mn*b[l] + sl*(1.f - b[l]), r);
            r = fmaf(pr[5], mx*b[l] + sl*(1.f - b[l]), r);
            r = fmaf(pr[6], vaS*f[l] + sl*(1.f - f[l]), r);
            o[l] = r;
        }
        *reinterpret_cast<float4*>(out_att + p*8)     = make_float4(o[0], o[1], o[2], o[3]);
        *reinterpret_cast<float4*>(out_att + p*8 + 4) = make_float4(o[4], o[5], o[6], o[7]);
    }

    if (t == 0) {
        const float cpp = pr[0] + pr[2] + pr[7];
        const float cf  = pr[1] + pr[6];
        const float cb  = pr[4] + pr[5] + pr[8];
        float pa[8];
        float m = -3.0e38f;
#pragma unroll
        for (int l = 0; l < 8; ++l) {
            pa[l] = cpp*pp[l] + cf*f[l] + cb*b[l] + pr[3]*fb[l];
            m = fmaxf(m, pa[l]);
        }
        float ssum = 0.f;
#pragma unroll
        for (int l = 0; l < 8; ++l) { pa[l] = __expf(pa[l] - m); ssum += pa[l]; }
#pragma unroll
        for (int l = 0; l < 8; ++l) out_ptr[n*8 + l] = pa[l] / ssum;
    }
}

// ================================================================
extern "C" void kernel_launch(void* const* d_in, const int* in_sizes, int n_in,
                              void* d_out, int out_size, void* d_ws, size_t ws_size,
                              hipStream_t stream)
{
    (void)in_sizes; (void)n_in; (void)out_size;
    const float* control = (const float*)d_in[0];
    const float* kb      = (const float*)d_in[1];
    const float* prob    = (const float*)d_in[2];
    const float* memprev = (const float*)d_in[3];
    const float* stk     = (const float*)d_in[4];
    const float* ptrp    = (const float*)d_in[5];
    const float* find_w  = (const float*)d_in[6];
    const float* find_b  = (const float*)d_in[7];
    const float* findc_w = (const float*)d_in[8];
    const float* findc_b = (const float*)d_in[9];
    const float* tr_w    = (const float*)d_in[10];
    const float* tr_b    = (const float*)d_in[11];
    const float* trc_w   = (const float*)d_in[12];
    const float* trc_b   = (const float*)d_in[13];
    const float* sc_w    = (const float*)d_in[14];
    const float* sc_b    = (const float*)d_in[15];
    const float* d1_w    = (const float*)d_in[16];
    const float* d1_b    = (const float*)d_in[17];
    const float* d1m_w   = (const float*)d_in[18];
    const float* d1m_b   = (const float*)d_in[19];
    const float* d2_w    = (const float*)d_in[20];
    const float* d2_b    = (const float*)d_in[21];
    const float* d2m_w   = (const float*)d_in[22];
    const float* d2m_b   = (const float*)d_in[23];

    if (ws_size < WS_FLOATS * sizeof(float)) return;

    float* ws    = (float*)d_ws;
    float* att1g = ws + OFF_ATT1;
    float* att2g = ws + OFF_ATT2;
    float* w1g   = ws + OFF_W1;
    float* w2g   = ws + OFF_W2;
    float* aF    = ws + OFF_AF;
    float* aT    = ws + OFF_AT;
    float* aS    = ws + OFF_AS;
    float* GP1   = ws + OFF_GP1;
    float* kpart = ws + OFF_KP;
    float* A1    = ws + OFF_A1;
    float* A2    = ws + OFF_A2;
    float* g     = ws + OFF_G;
    float* P2    = ws + OFF_P2;
    float* fws   = ws + OFF_PF;
    float* bws   = ws + OFF_PB;
    float* fbws  = ws + OFF_PFB;
    float* sf2   = ws + OFF_SF2;
    float* sffb  = ws + OFF_SFFB;

    float* out_att = (float*)d_out;
    float* out_ptr = out_att + (size_t)NB*HW*LSZ;
    float* out_mem = out_ptr + (size_t)NB*LSZ;

    // 1. k_att ∪ gemm1-partials
    k_front<<<256 + 512, 256, 0, stream>>>(
        stk, ptrp, att1g, att2g, w1g, w2g, fws, bws, fbws, sf2, sffb,
        control, find_w, tr_w, d1_w, d2_w, GP1);
    // 2. kb pass A (reduces its own c_find from GP1)
    k_kbA<<<NB*4, 256, 0, stream>>>(kb, GP1, find_b, findc_w, findc_b, sc_w, sc_b,
                                    w1g, w2g, aF, aS, kpart);
    // 3. katt reduce + c_tr/c_d1/c_d2 reduce + g/elts/A1'/A2'
    k_elt<<<NB, 256, 0, stream>>>(kpart, GP1, tr_b, d1_b, d2_b,
                                  control, prob, g, A1, A2);
    // 4. kb pass B ∪ fused mem-GEMM partials (mod-3 striped)
    k_mid<<<1536, 256, 0, stream>>>(kb, g, trc_w, trc_b, aT,
                                    A1, A2, d1m_w, d2m_w, P2);
    // 5. mem_avg ∪ att_stack_avg/stack_ptr_avg
    k_back<<<128 + 256, 256, 0, stream>>>(P2, memprev, prob, d1m_b, d2m_b, out_mem,
                                          stk, ptrp, att1g, att2g, aF, aT, aS,
                                          fws, bws, fbws, sf2, sffb, out_att, out_ptr);
}